// Round 1
// baseline (998.633 us; speedup 1.0000x reference)
//
#include <hip/hip_runtime.h>

#define NN 50000
#define NE 600000
#define NG 512
#define HD 128
#define EPSV 1e-5f

__device__ inline void atomicAddF(float* p, float v) {
  __hip_atomic_fetch_add(p, v, __ATOMIC_RELAXED, __HIP_MEMORY_SCOPE_AGENT);
}

// ---- CSR build ----
__global__ __launch_bounds__(256) void k_count(const int* __restrict__ dst, int* __restrict__ cnt) {
  int e = blockIdx.x * 256 + threadIdx.x;
  if (e < NE) atomicAdd(&cnt[dst[e]], 1);
}

__global__ __launch_bounds__(1024) void k_scan(const int* __restrict__ cnt, int* __restrict__ off,
                                               int* __restrict__ cursor, float* __restrict__ dinv) {
  __shared__ int part[16];
  __shared__ int partscan[16];
  int t = threadIdx.x;
  int lane = t & 63, w = t >> 6;
  int carry = 0;
  for (int base = 0; base < NN; base += 1024) {
    int idx = base + t;
    int v = (idx < NN) ? cnt[idx] : 0;
    int val = v;
#pragma unroll
    for (int s = 1; s < 64; s <<= 1) {
      int u = __shfl_up(val, s);
      if (lane >= s) val += u;
    }
    if (lane == 63) part[w] = val;
    __syncthreads();
    if (t == 0) {
      int acc = 0;
#pragma unroll
      for (int i = 0; i < 16; i++) { acc += part[i]; partscan[i] = acc; }
    }
    __syncthreads();
    int waveoff = (w > 0) ? partscan[w - 1] : 0;
    int incl = val + waveoff + carry;
    if (idx < NN) {
      off[idx] = incl - v;
      cursor[idx] = incl - v;
      dinv[idx] = rsqrtf((float)v + 1.0f);
    }
    carry += partscan[15];
    __syncthreads();
  }
  if (t == 0) off[NN] = carry;
}

__global__ __launch_bounds__(256) void k_fill(const int* __restrict__ src, const int* __restrict__ dst,
                                              int* __restrict__ cursor, int* __restrict__ csr) {
  int e = blockIdx.x * 256 + threadIdx.x;
  if (e < NE) {
    int p = atomicAdd(&cursor[dst[e]], 1);
    csr[p] = src[e];
  }
}

// ---- fused embedding tables: T = emb @ W1[rows] ----
__global__ __launch_bounds__(128) void k_tabs(const float* __restrict__ emb0, const float* __restrict__ emb1,
                                              const float* __restrict__ emb2, const float* __restrict__ emb5,
                                              const float* __restrict__ W1, float* __restrict__ tabs,
                                              float* __restrict__ row0) {
  int r = blockIdx.x, f = threadIdx.x;
  if (r == 470) { row0[f] = W1[f]; return; }
  const float* e;
  int wbase;
  if (r < 96)      { e = emb0 + r * 32;        wbase = 1;  }
  else if (r < 192){ e = emb1 + (r - 96) * 32; wbase = 33; }
  else if (r < 288){ e = emb2 + (r - 192) * 32; wbase = 65; }
  else             { e = emb5 + (r - 288) * 32; wbase = 97; }
  float acc = 0.f;
#pragma unroll 8
  for (int k = 0; k < 32; k++) acc += e[k] * W1[(wbase + k) * HD + f];
  tabs[r * HD + f] = acc;
}

// ---- layer-1: embed + axpy + pre-scale by dinv ----
__global__ __launch_bounds__(256) void k_embed(const float* __restrict__ x, const float* __restrict__ tabs,
                                               const float* __restrict__ row0, const float* __restrict__ dinv,
                                               float* __restrict__ A) {
  int n = blockIdx.x * 2 + (threadIdx.x >> 7);
  int f = threadIdx.x & 127;
  if (n >= NN) return;
  float poss = x[n * 5 + 0];
  int i0 = (int)x[n * 5 + 1];
  int i1 = (int)x[n * 5 + 2];
  int i2 = (int)x[n * 5 + 3];
  int i5 = (int)x[n * 5 + 4];
  float hw = poss * row0[f] + tabs[i0 * HD + f] + tabs[(96 + i1) * HD + f] +
             tabs[(192 + i2) * HD + f] + tabs[(288 + i5) * HD + f];
  A[n * HD + f] = hw * dinv[n];
}

// ---- aggregation: B[n] = dinv[n]*(A[n] + sum_in A[src]) + b; fused BN stats ----
__global__ __launch_bounds__(256) void k_agg(const float* __restrict__ A, const int* __restrict__ off,
                                             const int* __restrict__ csr, const float* __restrict__ dinv,
                                             const float* __restrict__ bias, float* __restrict__ B,
                                             float* __restrict__ stats) {
  int f = threadIdx.x & 127;
  int half = threadIdx.x >> 7;
  int base = blockIdx.x * 64;
  float s1 = 0.f, s2 = 0.f;
  float bf = bias[f];
  for (int i = half; i < 64; i += 2) {
    int n = base + i;
    if (n >= NN) break;
    float acc = A[n * HD + f];
    int ks = off[n], ke = off[n + 1];
    for (int k = ks; k < ke; k++) {
      int srcn = csr[k];
      acc += A[srcn * HD + f];
    }
    float out = acc * dinv[n] + bf;
    B[n * HD + f] = out;
    s1 += out;
    s2 += out * out;
  }
  __shared__ float red[256];
  red[threadIdx.x] = s1;
  __syncthreads();
  float t1 = 0.f;
  if (half == 0) t1 = red[f] + red[f + 128];
  __syncthreads();
  red[threadIdx.x] = s2;
  __syncthreads();
  if (half == 0) {
    float t2 = red[f] + red[f + 128];
    atomicAddF(&stats[f], t1);
    atomicAddF(&stats[128 + f], t2);
  }
}

// ---- BN finalize -> affine a,c ----
__global__ __launch_bounds__(128) void k_affine(const float* __restrict__ stats, const float* __restrict__ g,
                                                const float* __restrict__ be, float* __restrict__ af,
                                                float* __restrict__ cf) {
  int f = threadIdx.x;
  float mean = stats[f] * (1.f / NN);
  float var = stats[128 + f] * (1.f / NN) - mean * mean;
  var = fmaxf(var, 0.f);
  float inv = rsqrtf(var + EPSV);
  float a = g[f] * inv;
  af[f] = a;
  cf[f] = be[f] - mean * a;
}

// ---- GEMM: Aout[n,:] = dinv[n] * (relu(af*Bin[n,:]+cf) @ W) ----
__global__ __launch_bounds__(256) void k_gemm(const float* __restrict__ Bin, const float* __restrict__ W,
                                              const float* __restrict__ af, const float* __restrict__ cf,
                                              const float* __restrict__ dinv, float* __restrict__ Aout) {
  __shared__ float lds_h[64 * 132];
  __shared__ float lds_w[128 * 128];
  int t = threadIdx.x;
  int base = blockIdx.x * 64;
  {
    const float4* W4 = (const float4*)W;
    float4* L4 = (float4*)lds_w;
    for (int i = t; i < 128 * 128 / 4; i += 256) L4[i] = W4[i];
  }
  for (int i = t; i < 64 * 128 / 4; i += 256) {
    int node = i >> 5;
    int c4 = i & 31;
    int n = base + node;
    float4 v = make_float4(0.f, 0.f, 0.f, 0.f);
    if (n < NN) v = ((const float4*)(Bin + (size_t)n * HD))[c4];
    int k0 = c4 * 4;
    float4 r;
    r.x = fmaxf(af[k0 + 0] * v.x + cf[k0 + 0], 0.f);
    r.y = fmaxf(af[k0 + 1] * v.y + cf[k0 + 1], 0.f);
    r.z = fmaxf(af[k0 + 2] * v.z + cf[k0 + 2], 0.f);
    r.w = fmaxf(af[k0 + 3] * v.w + cf[k0 + 3], 0.f);
    ((float4*)(lds_h + node * 132))[c4] = r;
  }
  __syncthreads();
  int tx = t & 15;
  int ny = t >> 4;
  float acc[4][8];
#pragma unroll
  for (int j = 0; j < 4; j++)
#pragma unroll
    for (int c = 0; c < 8; c++) acc[j][c] = 0.f;
#pragma unroll 4
  for (int k = 0; k < 128; k++) {
    float hk[4];
#pragma unroll
    for (int j = 0; j < 4; j++) hk[j] = lds_h[(ny * 4 + j) * 132 + k];
    float4 w0 = ((const float4*)(lds_w + k * HD))[tx];
    float4 w1 = ((const float4*)(lds_w + k * HD + 64))[tx];
#pragma unroll
    for (int j = 0; j < 4; j++) {
      acc[j][0] += hk[j] * w0.x;
      acc[j][1] += hk[j] * w0.y;
      acc[j][2] += hk[j] * w0.z;
      acc[j][3] += hk[j] * w0.w;
      acc[j][4] += hk[j] * w1.x;
      acc[j][5] += hk[j] * w1.y;
      acc[j][6] += hk[j] * w1.z;
      acc[j][7] += hk[j] * w1.w;
    }
  }
#pragma unroll
  for (int j = 0; j < 4; j++) {
    int n = base + ny * 4 + j;
    if (n < NN) {
      float s = dinv[n];
      float4 o0 = make_float4(acc[j][0] * s, acc[j][1] * s, acc[j][2] * s, acc[j][3] * s);
      float4 o1 = make_float4(acc[j][4] * s, acc[j][5] * s, acc[j][6] * s, acc[j][7] * s);
      ((float4*)(Aout + (size_t)n * HD))[tx] = o0;
      ((float4*)(Aout + (size_t)n * HD + 64))[tx] = o1;
    }
  }
}

// ---- graph boundaries via binary search on sorted batch ----
__global__ __launch_bounds__(128) void k_bsearch(const int* __restrict__ batch, int* __restrict__ gstart) {
  int g = blockIdx.x * 128 + threadIdx.x;
  if (g > NG) return;
  if (g == NG) { gstart[NG] = NN; return; }
  int lo = 0, hi = NN;
  while (lo < hi) {
    int mid = (lo + hi) >> 1;
    if (batch[mid] < g) lo = mid + 1;
    else hi = mid;
  }
  gstart[g] = lo;
}

// ---- pool + FC ----
__global__ __launch_bounds__(128) void k_pool(const float* __restrict__ B, const float* __restrict__ af,
                                              const float* __restrict__ cf, const int* __restrict__ gstart,
                                              const float* __restrict__ fcW, const float* __restrict__ fcb,
                                              float* __restrict__ out) {
  int g = blockIdx.x, f = threadIdx.x;
  int gs = gstart[g], ge = gstart[g + 1];
  float a = af[f], c = cf[f];
  float acc = 0.f;
  for (int n = gs; n < ge; n++) acc += fmaxf(a * B[(size_t)n * HD + f] + c, 0.f);
  float cntf = (float)(ge - gs);
  float pooled = acc / fmaxf(cntf, 1.f);
  __shared__ float lp[128];
  lp[f] = pooled;
  __syncthreads();
  if (f < 3) {
    float o = fcb[f];
    for (int k = 0; k < 128; k++) o += lp[k] * fcW[k * 3 + f];
    out[g * 3 + f] = o;
  }
}

extern "C" void kernel_launch(void* const* d_in, const int* in_sizes, int n_in,
                              void* d_out, int out_size, void* d_ws, size_t ws_size,
                              hipStream_t stream) {
  const float* x    = (const float*)d_in[0];
  const int* ei     = (const int*)d_in[1];
  const int* batch  = (const int*)d_in[2];
  const float* emb0 = (const float*)d_in[3];
  const float* emb1 = (const float*)d_in[4];
  const float* emb2 = (const float*)d_in[5];
  const float* emb5 = (const float*)d_in[6];
  const float* W1   = (const float*)d_in[7];
  const float* b1   = (const float*)d_in[8];
  const float* W2   = (const float*)d_in[9];
  const float* b2   = (const float*)d_in[10];
  const float* W3   = (const float*)d_in[11];
  const float* b3   = (const float*)d_in[12];
  const float* g1   = (const float*)d_in[13];
  const float* be1  = (const float*)d_in[14];
  const float* g2   = (const float*)d_in[15];
  const float* be2  = (const float*)d_in[16];
  const float* g3   = (const float*)d_in[17];
  const float* be3  = (const float*)d_in[18];
  const float* fcW  = (const float*)d_in[19];
  const float* fcb  = (const float*)d_in[20];
  float* out = (float*)d_out;

  const int* esrc = ei;
  const int* edst = ei + NE;

  char* p = (char*)d_ws;
  size_t o = 0;
  auto alloc = [&](size_t bytes) -> void* {
    o = (o + 255) & ~(size_t)255;
    void* r = p + o;
    o += bytes;
    return r;
  };
  int* cnt      = (int*)alloc(NN * 4);
  float* stats  = (float*)alloc(3 * 256 * 4);   // 3 layers x (sum,sumsq)
  size_t zbytes = o;                            // memset range covers cnt+stats
  int* off      = (int*)alloc((NN + 1) * 4);
  int* cursor   = (int*)alloc(NN * 4);
  int* csr      = (int*)alloc(NE * 4);
  float* dinv   = (float*)alloc(NN * 4);
  float* tabs   = (float*)alloc(470 * HD * 4);
  float* row0   = (float*)alloc(HD * 4);
  float* affine = (float*)alloc(3 * 256 * 4);   // 3 layers x (a,c)
  int* gstart   = (int*)alloc((NG + 1) * 4);
  float* bufA   = (float*)alloc((size_t)NN * HD * 4);
  float* bufB   = (float*)alloc((size_t)NN * HD * 4);
  (void)ws_size; (void)n_in; (void)in_sizes; (void)out_size;

  hipMemsetAsync(d_ws, 0, zbytes, stream);

  k_count<<<(NE + 255) / 256, 256, 0, stream>>>(edst, cnt);
  k_scan<<<1, 1024, 0, stream>>>(cnt, off, cursor, dinv);
  k_fill<<<(NE + 255) / 256, 256, 0, stream>>>(esrc, edst, cursor, csr);
  k_tabs<<<471, 128, 0, stream>>>(emb0, emb1, emb2, emb5, W1, tabs, row0);
  k_bsearch<<<5, 128, 0, stream>>>(batch, gstart);
  k_embed<<<NN / 2, 256, 0, stream>>>(x, tabs, row0, dinv, bufA);

  const int nagg = (NN + 63) / 64;

  // layer 1
  k_agg<<<nagg, 256, 0, stream>>>(bufA, off, csr, dinv, b1, bufB, stats + 0);
  k_affine<<<1, 128, 0, stream>>>(stats + 0, g1, be1, affine + 0, affine + 128);
  // layer 2
  k_gemm<<<nagg, 256, 0, stream>>>(bufB, W2, affine + 0, affine + 128, dinv, bufA);
  k_agg<<<nagg, 256, 0, stream>>>(bufA, off, csr, dinv, b2, bufB, stats + 256);
  k_affine<<<1, 128, 0, stream>>>(stats + 256, g2, be2, affine + 256, affine + 384);
  // layer 3
  k_gemm<<<nagg, 256, 0, stream>>>(bufB, W3, affine + 256, affine + 384, dinv, bufA);
  k_agg<<<nagg, 256, 0, stream>>>(bufA, off, csr, dinv, b3, bufB, stats + 512);
  k_affine<<<1, 128, 0, stream>>>(stats + 512, g3, be3, affine + 512, affine + 640);
  // pool + fc
  k_pool<<<NG, 128, 0, stream>>>(bufB, affine + 512, affine + 640, gstart, fcW, fcb, out);
}

// Round 2
// 721.049 us; speedup vs baseline: 1.3850x; 1.3850x over previous
//
#include <hip/hip_runtime.h>

#define NN 50000
#define NE 600000
#define NG 512
#define HD 128
#define EPSV 1e-5f

__device__ inline void atomicAddF(float* p, float v) {
  __hip_atomic_fetch_add(p, v, __ATOMIC_RELAXED, __HIP_MEMORY_SCOPE_AGENT);
}

// ---- CSR build ----
__global__ __launch_bounds__(256) void k_count(const int* __restrict__ dst, int* __restrict__ cnt) {
  int e = blockIdx.x * 256 + threadIdx.x;
  if (e < NE) atomicAdd(&cnt[dst[e]], 1);
}

__global__ __launch_bounds__(1024) void k_scan(const int* __restrict__ cnt, int* __restrict__ off,
                                               int* __restrict__ cursor, float* __restrict__ dinv) {
  __shared__ int part[16];
  __shared__ int partscan[16];
  int t = threadIdx.x;
  int lane = t & 63, w = t >> 6;
  int carry = 0;
  for (int base = 0; base < NN; base += 1024) {
    int idx = base + t;
    int v = (idx < NN) ? cnt[idx] : 0;
    int val = v;
#pragma unroll
    for (int s = 1; s < 64; s <<= 1) {
      int u = __shfl_up(val, s);
      if (lane >= s) val += u;
    }
    if (lane == 63) part[w] = val;
    __syncthreads();
    if (t == 0) {
      int acc = 0;
#pragma unroll
      for (int i = 0; i < 16; i++) { acc += part[i]; partscan[i] = acc; }
    }
    __syncthreads();
    int waveoff = (w > 0) ? partscan[w - 1] : 0;
    int incl = val + waveoff + carry;
    if (idx < NN) {
      off[idx] = incl - v;
      cursor[idx] = incl - v;
      dinv[idx] = rsqrtf((float)v + 1.0f);
    }
    carry += partscan[15];
    __syncthreads();
  }
  if (t == 0) off[NN] = carry;
}

__global__ __launch_bounds__(256) void k_fill(const int* __restrict__ src, const int* __restrict__ dst,
                                              int* __restrict__ cursor, int* __restrict__ csr) {
  int e = blockIdx.x * 256 + threadIdx.x;
  if (e < NE) {
    int p = atomicAdd(&cursor[dst[e]], 1);
    csr[p] = src[e];
  }
}

// ---- fused embedding tables: T = emb @ W1[rows] ----
__global__ __launch_bounds__(128) void k_tabs(const float* __restrict__ emb0, const float* __restrict__ emb1,
                                              const float* __restrict__ emb2, const float* __restrict__ emb5,
                                              const float* __restrict__ W1, float* __restrict__ tabs,
                                              float* __restrict__ row0) {
  int r = blockIdx.x, f = threadIdx.x;
  if (r == 470) { row0[f] = W1[f]; return; }
  const float* e;
  int wbase;
  if (r < 96)      { e = emb0 + r * 32;        wbase = 1;  }
  else if (r < 192){ e = emb1 + (r - 96) * 32; wbase = 33; }
  else if (r < 288){ e = emb2 + (r - 192) * 32; wbase = 65; }
  else             { e = emb5 + (r - 288) * 32; wbase = 97; }
  float acc = 0.f;
#pragma unroll 8
  for (int k = 0; k < 32; k++) acc += e[k] * W1[(wbase + k) * HD + f];
  tabs[r * HD + f] = acc;
}

// ---- layer-1: embed + axpy + pre-scale by dinv ----
__global__ __launch_bounds__(256) void k_embed(const float* __restrict__ x, const float* __restrict__ tabs,
                                               const float* __restrict__ row0, const float* __restrict__ dinv,
                                               float* __restrict__ A) {
  int n = blockIdx.x * 2 + (threadIdx.x >> 7);
  int f = threadIdx.x & 127;
  if (n >= NN) return;
  float poss = x[n * 5 + 0];
  int i0 = (int)x[n * 5 + 1];
  int i1 = (int)x[n * 5 + 2];
  int i2 = (int)x[n * 5 + 3];
  int i5 = (int)x[n * 5 + 4];
  float hw = poss * row0[f] + tabs[i0 * HD + f] + tabs[(96 + i1) * HD + f] +
             tabs[(192 + i2) * HD + f] + tabs[(288 + i5) * HD + f];
  A[n * HD + f] = hw * dinv[n];
}

// ---- aggregation: wave-per-node, batched index broadcast, ILP-8 gathers ----
// B[n] = dinv[n]*(A[n] + sum_in A[src]) + b; fused BN stats.
#define AGG_NPW 6           // nodes per wave
#define AGG_NPB (4 * AGG_NPW)
__global__ __launch_bounds__(256) void k_agg(const float* __restrict__ A, const int* __restrict__ off,
                                             const int* __restrict__ csr, const float* __restrict__ dinv,
                                             const float* __restrict__ bias, float* __restrict__ B,
                                             float* __restrict__ stats) {
  const int t = threadIdx.x;
  const int lane = t & 63;
  const int wave = t >> 6;
  const float2* __restrict__ A2 = (const float2*)A;
  float2* __restrict__ B2 = (float2*)B;
  const float2 bias2 = ((const float2*)bias)[lane];

  float2 s1 = make_float2(0.f, 0.f);
  float2 s2 = make_float2(0.f, 0.f);

  int nbase = blockIdx.x * AGG_NPB + wave * AGG_NPW;
  for (int i = 0; i < AGG_NPW; i++) {
    int n = nbase + i;
    if (n >= NN) break;
    int ks = off[n], ke = off[n + 1];
    float2 acc = A2[(size_t)n * 64 + lane];  // self contribution (pre-scaled)
    for (int kb = ks; kb < ke; kb += 64) {
      int cnt = min(64, ke - kb);
      int myidx = (lane < cnt) ? csr[kb + lane] : 0;
      int k = 0;
      for (; k + 8 <= cnt; k += 8) {
        int s0 = __shfl(myidx, k + 0), s1i = __shfl(myidx, k + 1);
        int s2i = __shfl(myidx, k + 2), s3 = __shfl(myidx, k + 3);
        int s4 = __shfl(myidx, k + 4), s5 = __shfl(myidx, k + 5);
        int s6 = __shfl(myidx, k + 6), s7 = __shfl(myidx, k + 7);
        float2 v0 = A2[(size_t)s0 * 64 + lane];
        float2 v1 = A2[(size_t)s1i * 64 + lane];
        float2 v2 = A2[(size_t)s2i * 64 + lane];
        float2 v3 = A2[(size_t)s3 * 64 + lane];
        float2 v4 = A2[(size_t)s4 * 64 + lane];
        float2 v5 = A2[(size_t)s5 * 64 + lane];
        float2 v6 = A2[(size_t)s6 * 64 + lane];
        float2 v7 = A2[(size_t)s7 * 64 + lane];
        acc.x += ((v0.x + v1.x) + (v2.x + v3.x)) + ((v4.x + v5.x) + (v6.x + v7.x));
        acc.y += ((v0.y + v1.y) + (v2.y + v3.y)) + ((v4.y + v5.y) + (v6.y + v7.y));
      }
      for (; k + 4 <= cnt; k += 4) {
        int s0 = __shfl(myidx, k + 0), s1i = __shfl(myidx, k + 1);
        int s2i = __shfl(myidx, k + 2), s3 = __shfl(myidx, k + 3);
        float2 v0 = A2[(size_t)s0 * 64 + lane];
        float2 v1 = A2[(size_t)s1i * 64 + lane];
        float2 v2 = A2[(size_t)s2i * 64 + lane];
        float2 v3 = A2[(size_t)s3 * 64 + lane];
        acc.x += (v0.x + v1.x) + (v2.x + v3.x);
        acc.y += (v0.y + v1.y) + (v2.y + v3.y);
      }
      for (; k < cnt; k++) {
        int s0 = __shfl(myidx, k);
        float2 v0 = A2[(size_t)s0 * 64 + lane];
        acc.x += v0.x;
        acc.y += v0.y;
      }
    }
    float dv = dinv[n];
    float2 outv;
    outv.x = acc.x * dv + bias2.x;
    outv.y = acc.y * dv + bias2.y;
    B2[(size_t)n * 64 + lane] = outv;
    s1.x += outv.x; s1.y += outv.y;
    s2.x += outv.x * outv.x; s2.y += outv.y * outv.y;
  }

  // block-level BN-stat reduction: 4 waves cover the same 128 features
  __shared__ float2 red[256];
  red[t] = s1;
  __syncthreads();
  float2 t1;
  if (wave == 0) {
    t1.x = red[lane].x + red[lane + 64].x + red[lane + 128].x + red[lane + 192].x;
    t1.y = red[lane].y + red[lane + 64].y + red[lane + 128].y + red[lane + 192].y;
  }
  __syncthreads();
  red[t] = s2;
  __syncthreads();
  if (wave == 0) {
    float2 t2;
    t2.x = red[lane].x + red[lane + 64].x + red[lane + 128].x + red[lane + 192].x;
    t2.y = red[lane].y + red[lane + 64].y + red[lane + 128].y + red[lane + 192].y;
    atomicAddF(&stats[2 * lane + 0], t1.x);
    atomicAddF(&stats[2 * lane + 1], t1.y);
    atomicAddF(&stats[128 + 2 * lane + 0], t2.x);
    atomicAddF(&stats[128 + 2 * lane + 1], t2.y);
  }
}

// ---- BN finalize -> affine a,c ----
__global__ __launch_bounds__(128) void k_affine(const float* __restrict__ stats, const float* __restrict__ g,
                                                const float* __restrict__ be, float* __restrict__ af,
                                                float* __restrict__ cf) {
  int f = threadIdx.x;
  float mean = stats[f] * (1.f / NN);
  float var = stats[128 + f] * (1.f / NN) - mean * mean;
  var = fmaxf(var, 0.f);
  float inv = rsqrtf(var + EPSV);
  float a = g[f] * inv;
  af[f] = a;
  cf[f] = be[f] - mean * a;
}

// ---- GEMM: Aout[n,:] = dinv[n] * (relu(af*Bin[n,:]+cf) @ W) ----
__global__ __launch_bounds__(256) void k_gemm(const float* __restrict__ Bin, const float* __restrict__ W,
                                              const float* __restrict__ af, const float* __restrict__ cf,
                                              const float* __restrict__ dinv, float* __restrict__ Aout) {
  __shared__ float lds_h[64 * 132];
  __shared__ float lds_w[128 * 128];
  int t = threadIdx.x;
  int base = blockIdx.x * 64;
  {
    const float4* W4 = (const float4*)W;
    float4* L4 = (float4*)lds_w;
    for (int i = t; i < 128 * 128 / 4; i += 256) L4[i] = W4[i];
  }
  for (int i = t; i < 64 * 128 / 4; i += 256) {
    int node = i >> 5;
    int c4 = i & 31;
    int n = base + node;
    float4 v = make_float4(0.f, 0.f, 0.f, 0.f);
    if (n < NN) v = ((const float4*)(Bin + (size_t)n * HD))[c4];
    int k0 = c4 * 4;
    float4 r;
    r.x = fmaxf(af[k0 + 0] * v.x + cf[k0 + 0], 0.f);
    r.y = fmaxf(af[k0 + 1] * v.y + cf[k0 + 1], 0.f);
    r.z = fmaxf(af[k0 + 2] * v.z + cf[k0 + 2], 0.f);
    r.w = fmaxf(af[k0 + 3] * v.w + cf[k0 + 3], 0.f);
    ((float4*)(lds_h + node * 132))[c4] = r;
  }
  __syncthreads();
  int tx = t & 15;
  int ny = t >> 4;
  float acc[4][8];
#pragma unroll
  for (int j = 0; j < 4; j++)
#pragma unroll
    for (int c = 0; c < 8; c++) acc[j][c] = 0.f;
#pragma unroll 4
  for (int k = 0; k < 128; k++) {
    float hk[4];
#pragma unroll
    for (int j = 0; j < 4; j++) hk[j] = lds_h[(ny * 4 + j) * 132 + k];
    float4 w0 = ((const float4*)(lds_w + k * HD))[tx];
    float4 w1 = ((const float4*)(lds_w + k * HD + 64))[tx];
#pragma unroll
    for (int j = 0; j < 4; j++) {
      acc[j][0] += hk[j] * w0.x;
      acc[j][1] += hk[j] * w0.y;
      acc[j][2] += hk[j] * w0.z;
      acc[j][3] += hk[j] * w0.w;
      acc[j][4] += hk[j] * w1.x;
      acc[j][5] += hk[j] * w1.y;
      acc[j][6] += hk[j] * w1.z;
      acc[j][7] += hk[j] * w1.w;
    }
  }
#pragma unroll
  for (int j = 0; j < 4; j++) {
    int n = base + ny * 4 + j;
    if (n < NN) {
      float s = dinv[n];
      float4 o0 = make_float4(acc[j][0] * s, acc[j][1] * s, acc[j][2] * s, acc[j][3] * s);
      float4 o1 = make_float4(acc[j][4] * s, acc[j][5] * s, acc[j][6] * s, acc[j][7] * s);
      ((float4*)(Aout + (size_t)n * HD))[tx] = o0;
      ((float4*)(Aout + (size_t)n * HD + 64))[tx] = o1;
    }
  }
}

// ---- graph boundaries via binary search on sorted batch ----
__global__ __launch_bounds__(128) void k_bsearch(const int* __restrict__ batch, int* __restrict__ gstart) {
  int g = blockIdx.x * 128 + threadIdx.x;
  if (g > NG) return;
  if (g == NG) { gstart[NG] = NN; return; }
  int lo = 0, hi = NN;
  while (lo < hi) {
    int mid = (lo + hi) >> 1;
    if (batch[mid] < g) lo = mid + 1;
    else hi = mid;
  }
  gstart[g] = lo;
}

// ---- pool + FC ----
__global__ __launch_bounds__(128) void k_pool(const float* __restrict__ B, const float* __restrict__ af,
                                              const float* __restrict__ cf, const int* __restrict__ gstart,
                                              const float* __restrict__ fcW, const float* __restrict__ fcb,
                                              float* __restrict__ out) {
  int g = blockIdx.x, f = threadIdx.x;
  int gs = gstart[g], ge = gstart[g + 1];
  float a = af[f], c = cf[f];
  float acc = 0.f;
  for (int n = gs; n < ge; n++) acc += fmaxf(a * B[(size_t)n * HD + f] + c, 0.f);
  float cntf = (float)(ge - gs);
  float pooled = acc / fmaxf(cntf, 1.f);
  __shared__ float lp[128];
  lp[f] = pooled;
  __syncthreads();
  if (f < 3) {
    float o = fcb[f];
    for (int k = 0; k < 128; k++) o += lp[k] * fcW[k * 3 + f];
    out[g * 3 + f] = o;
  }
}

extern "C" void kernel_launch(void* const* d_in, const int* in_sizes, int n_in,
                              void* d_out, int out_size, void* d_ws, size_t ws_size,
                              hipStream_t stream) {
  const float* x    = (const float*)d_in[0];
  const int* ei     = (const int*)d_in[1];
  const int* batch  = (const int*)d_in[2];
  const float* emb0 = (const float*)d_in[3];
  const float* emb1 = (const float*)d_in[4];
  const float* emb2 = (const float*)d_in[5];
  const float* emb5 = (const float*)d_in[6];
  const float* W1   = (const float*)d_in[7];
  const float* b1   = (const float*)d_in[8];
  const float* W2   = (const float*)d_in[9];
  const float* b2   = (const float*)d_in[10];
  const float* W3   = (const float*)d_in[11];
  const float* b3   = (const float*)d_in[12];
  const float* g1   = (const float*)d_in[13];
  const float* be1  = (const float*)d_in[14];
  const float* g2   = (const float*)d_in[15];
  const float* be2  = (const float*)d_in[16];
  const float* g3   = (const float*)d_in[17];
  const float* be3  = (const float*)d_in[18];
  const float* fcW  = (const float*)d_in[19];
  const float* fcb  = (const float*)d_in[20];
  float* out = (float*)d_out;

  const int* esrc = ei;
  const int* edst = ei + NE;

  char* p = (char*)d_ws;
  size_t o = 0;
  auto alloc = [&](size_t bytes) -> void* {
    o = (o + 255) & ~(size_t)255;
    void* r = p + o;
    o += bytes;
    return r;
  };
  int* cnt      = (int*)alloc(NN * 4);
  float* stats  = (float*)alloc(3 * 256 * 4);   // 3 layers x (sum,sumsq)
  size_t zbytes = o;                            // memset range covers cnt+stats
  int* off      = (int*)alloc((NN + 1) * 4);
  int* cursor   = (int*)alloc(NN * 4);
  int* csr      = (int*)alloc(NE * 4);
  float* dinv   = (float*)alloc(NN * 4);
  float* tabs   = (float*)alloc(470 * HD * 4);
  float* row0   = (float*)alloc(HD * 4);
  float* affine = (float*)alloc(3 * 256 * 4);   // 3 layers x (a,c)
  int* gstart   = (int*)alloc((NG + 1) * 4);
  float* bufA   = (float*)alloc((size_t)NN * HD * 4);
  float* bufB   = (float*)alloc((size_t)NN * HD * 4);
  (void)ws_size; (void)n_in; (void)in_sizes; (void)out_size;

  hipMemsetAsync(d_ws, 0, zbytes, stream);

  k_count<<<(NE + 255) / 256, 256, 0, stream>>>(edst, cnt);
  k_scan<<<1, 1024, 0, stream>>>(cnt, off, cursor, dinv);
  k_fill<<<(NE + 255) / 256, 256, 0, stream>>>(esrc, edst, cursor, csr);
  k_tabs<<<471, 128, 0, stream>>>(emb0, emb1, emb2, emb5, W1, tabs, row0);
  k_bsearch<<<5, 128, 0, stream>>>(batch, gstart);
  k_embed<<<NN / 2, 256, 0, stream>>>(x, tabs, row0, dinv, bufA);

  const int nagg = (NN + AGG_NPB - 1) / AGG_NPB;
  const int ngemm = (NN + 63) / 64;

  // layer 1
  k_agg<<<nagg, 256, 0, stream>>>(bufA, off, csr, dinv, b1, bufB, stats + 0);
  k_affine<<<1, 128, 0, stream>>>(stats + 0, g1, be1, affine + 0, affine + 128);
  // layer 2
  k_gemm<<<ngemm, 256, 0, stream>>>(bufB, W2, affine + 0, affine + 128, dinv, bufA);
  k_agg<<<nagg, 256, 0, stream>>>(bufA, off, csr, dinv, b2, bufB, stats + 256);
  k_affine<<<1, 128, 0, stream>>>(stats + 256, g2, be2, affine + 256, affine + 384);
  // layer 3
  k_gemm<<<ngemm, 256, 0, stream>>>(bufB, W3, affine + 256, affine + 384, dinv, bufA);
  k_agg<<<nagg, 256, 0, stream>>>(bufA, off, csr, dinv, b3, bufB, stats + 512);
  k_affine<<<1, 128, 0, stream>>>(stats + 512, g3, be3, affine + 512, affine + 640);
  // pool + fc
  k_pool<<<NG, 128, 0, stream>>>(bufB, affine + 512, affine + 640, gstart, fcW, fcb, out);
}